// Round 2
// baseline (283.421 us; speedup 1.0000x reference)
//
#include <hip/hip_runtime.h>

// Problem constants (match reference)
#define BB    8
#define NMAX  128
#define HH    192
#define WW    256

// Antiderivative of the bilinear hat kernel, with clipping.
__device__ __forceinline__ float hatP(float u) {
    u = fminf(fmaxf(u, -1.0f), 1.0f);
    return (u <= 0.0f) ? 0.5f * (u + 1.0f) * (u + 1.0f)
                       : 0.5f + u - 0.5f * u * u;
}

// Fused: one block per box; per-image accumulation via device-scope float
// atomics (executed at the coherence point -> no cross-XCD staleness); the
// last block (elected via atomic counter) folds the 8 per-image values into
// the scalar loss. Workspace layout: err_acc[8] | val_acc[8] | counter.
__global__ __launch_bounds__(256)
void dnc_loss_fused_kernel(const float* __restrict__ den,    // [B,1,H,W]
                           const float* __restrict__ hboxes, // [B,N,5]
                           const float* __restrict__ post,   // [B,N,H,W]
                           float* __restrict__ err_acc,      // [B]
                           float* __restrict__ val_acc,      // [B]
                           unsigned int* __restrict__ counter,
                           float* __restrict__ out) {        // [1]
    const int bn = blockIdx.x;           // b*NMAX + n
    const int b  = bn >> 7;              // NMAX == 128

    const float* box = hboxes + bn * 5;
    const float x1 = box[0] * 0.125f;
    const float y1 = box[1] * 0.125f;
    const float x2 = box[2] * 0.125f;
    const float y2 = box[3] * 0.125f;
    const float valid = (box[4] > 0.0f) ? 1.0f : 0.0f;

    // Support of the hat-integral weights (exactly zero outside (lo-1, hi+1)).
    const int ix0 = max(0,      (int)ceilf (x1 - 1.0f));
    const int ix1 = min(WW - 1, (int)floorf(x2 + 1.0f));
    const int iy0 = max(0,      (int)ceilf (y1 - 1.0f));
    const int iy1 = min(HH - 1, (int)floorf(y2 + 1.0f));
    const int nx = ix1 - ix0 + 1;        // <= ~21
    const int ny = iy1 - iy0 + 1;        // <= ~21
    const int total = nx * ny;           // <= ~441

    const float* post_bn = post + (size_t)bn * HH * WW;
    const float* den_b   = den  + (size_t)b  * HH * WW;

    float acc = 0.0f;
    for (int t = threadIdx.x; t < total; t += 256) {
        const int iy = iy0 + t / nx;
        const int ix = ix0 + t % nx;
        const float wyv = hatP(y2 - (float)iy) - hatP(y1 - (float)iy);
        const float wxv = hatP(x2 - (float)ix) - hatP(x1 - (float)ix);
        const float d   = den_b  [iy * WW + ix];
        const float p   = post_bn[iy * WW + ix];
        acc += (wyv * wxv) * (d * p);
    }

    // Block reduction: wave64 shuffle, then 4-entry LDS.
    #pragma unroll
    for (int off = 32; off > 0; off >>= 1)
        acc += __shfl_down(acc, off, 64);

    __shared__ float smem[4];
    __shared__ int last_flag;
    const int wave = threadIdx.x >> 6;
    const int lane = threadIdx.x & 63;
    if (lane == 0) smem[wave] = acc;
    __syncthreads();

    if (threadIdx.x == 0) {
        const float cnt = smem[0] + smem[1] + smem[2] + smem[3];
        const float err = fabsf(cnt - 1.0f) * valid;
        atomicAdd(&err_acc[b], err);     // device-scope, coherence point
        atomicAdd(&val_acc[b], valid);
        __threadfence();                 // release before the ticket
        const unsigned int t = atomicAdd(counter, 1u);
        last_flag = (t == (unsigned int)(gridDim.x - 1));
    }
    __syncthreads();

    if (last_flag && threadIdx.x == 0) {
        __threadfence();                 // acquire after seeing final ticket
        float totalv = 0.0f;
        #pragma unroll
        for (int i = 0; i < BB; ++i) {
            // atomic reads -> coherence point, immune to stale per-XCD L2
            const float e = atomicAdd(&err_acc[i], 0.0f);
            const float v = atomicAdd(&val_acc[i], 0.0f);
            if (v > 0.0f) totalv += e / v;
        }
        out[0] = totalv;
    }
}

extern "C" void kernel_launch(void* const* d_in, const int* in_sizes, int n_in,
                              void* d_out, int out_size, void* d_ws, size_t ws_size,
                              hipStream_t stream) {
    // Input order: cls_preds(0) reg_preds(1) off_preds(2) den_preds(3)
    //              fboxes(4) hboxes(5) ctr_masks(6) post_probs(7)
    const float* den    = (const float*)d_in[3];
    const float* hboxes = (const float*)d_in[5];
    const float* post   = (const float*)d_in[7];
    float* out = (float*)d_out;

    float* err_acc = (float*)d_ws;                       // [8]
    float* val_acc = err_acc + BB;                       // [8]
    unsigned int* counter = (unsigned int*)(val_acc + BB);

    // Zero the 68 bytes of accumulators + ticket counter (ws is poisoned
    // to 0xAA before every timed launch). hipMemsetAsync is capture-safe.
    hipMemsetAsync(d_ws, 0, (2 * BB) * sizeof(float) + sizeof(unsigned int),
                   stream);

    dnc_loss_fused_kernel<<<BB * NMAX, 256, 0, stream>>>(
        den, hboxes, post, err_acc, val_acc, counter, out);
}

// Round 3
// 245.555 us; speedup vs baseline: 1.1542x; 1.1542x over previous
//
#include <hip/hip_runtime.h>

// Problem constants (match reference)
#define BB    8
#define NMAX  128
#define HH    192
#define WW    256

// Antiderivative of the bilinear hat kernel, with clipping.
__device__ __forceinline__ float hatP(float u) {
    u = fminf(fmaxf(u, -1.0f), 1.0f);
    return (u <= 0.0f) ? 0.5f * (u + 1.0f) * (u + 1.0f)
                       : 0.5f + u - 0.5f * u * u;
}

// One wave per box. Axis weights are exactly zero outside (lo-1, hi+1):
// support is <= ~21x21 grid points -> <= 7 points per lane. No LDS, no
// __syncthreads; wave shuffle reduction only.
__global__ __launch_bounds__(64)
void box_count_kernel(const float* __restrict__ den,    // [B,1,H,W]
                      const float* __restrict__ hboxes, // [B,N,5]
                      const float* __restrict__ post,   // [B,N,H,W]
                      float2* __restrict__ ev_out) {    // [B*N] {err, valid}
    const int bn = blockIdx.x;           // b*NMAX + n
    const int b  = bn >> 7;              // NMAX == 128

    const float* box = hboxes + bn * 5;
    const float x1 = box[0] * 0.125f;
    const float y1 = box[1] * 0.125f;
    const float x2 = box[2] * 0.125f;
    const float y2 = box[3] * 0.125f;
    const float valid = (box[4] > 0.0f) ? 1.0f : 0.0f;

    // Support of the hat-integral weights (exactly zero outside (lo-1, hi+1)).
    const int ix0 = max(0,      (int)ceilf (x1 - 1.0f));
    const int ix1 = min(WW - 1, (int)floorf(x2 + 1.0f));
    const int iy0 = max(0,      (int)ceilf (y1 - 1.0f));
    const int iy1 = min(HH - 1, (int)floorf(y2 + 1.0f));
    const int nx = ix1 - ix0 + 1;        // <= ~21
    const int ny = iy1 - iy0 + 1;        // <= ~21
    const int total = nx * ny;           // <= ~441

    const float* post_bn = post + (size_t)bn * HH * WW;
    const float* den_b   = den  + (size_t)b  * HH * WW;

    float acc = 0.0f;
    for (int t = threadIdx.x; t < total; t += 64) {
        const int iy = iy0 + t / nx;
        const int ix = ix0 + t % nx;
        const float wyv = hatP(y2 - (float)iy) - hatP(y1 - (float)iy);
        const float wxv = hatP(x2 - (float)ix) - hatP(x1 - (float)ix);
        const float d   = den_b  [iy * WW + ix];
        const float p   = post_bn[iy * WW + ix];
        acc += (wyv * wxv) * (d * p);
    }

    // Wave64 shuffle reduction.
    #pragma unroll
    for (int off = 32; off > 0; off >>= 1)
        acc += __shfl_down(acc, off, 64);

    if (threadIdx.x == 0) {
        const float cnt = acc;
        float2 ev;
        ev.x = fabsf(cnt - 1.0f) * valid;
        ev.y = valid;
        ev_out[bn] = ev;
    }
}

// Single wave: preload all partials as independent loads (one latency
// exposure), then per-image normalize and sum to the scalar loss.
__global__ __launch_bounds__(64)
void finalize_kernel(const float2* __restrict__ ev,    // [B*N]
                     float* __restrict__ out) {        // [1]
    const int lane = threadIdx.x;  // 64 threads, one wave

    float2 p0[BB], p1[BB];
    #pragma unroll
    for (int b = 0; b < BB; ++b) {
        p0[b] = ev[b * NMAX + lane];
        p1[b] = ev[b * NMAX + lane + 64];
    }

    float total = 0.0f;
    #pragma unroll
    for (int b = 0; b < BB; ++b) {
        float e = p0[b].x + p1[b].x;
        float v = p0[b].y + p1[b].y;
        #pragma unroll
        for (int off = 32; off > 0; off >>= 1) {
            e += __shfl_down(e, off, 64);
            v += __shfl_down(v, off, 64);
        }
        if (lane == 0 && v > 0.0f) total += e / v;
    }
    if (lane == 0) out[0] = total;
}

extern "C" void kernel_launch(void* const* d_in, const int* in_sizes, int n_in,
                              void* d_out, int out_size, void* d_ws, size_t ws_size,
                              hipStream_t stream) {
    // Input order: cls_preds(0) reg_preds(1) off_preds(2) den_preds(3)
    //              fboxes(4) hboxes(5) ctr_masks(6) post_probs(7)
    const float* den    = (const float*)d_in[3];
    const float* hboxes = (const float*)d_in[5];
    const float* post   = (const float*)d_in[7];
    float* out = (float*)d_out;

    float2* ev_ws = (float2*)d_ws;       // [B*N] {err, valid}

    box_count_kernel<<<BB * NMAX, 64, 0, stream>>>(den, hboxes, post, ev_ws);
    finalize_kernel<<<1, 64, 0, stream>>>(ev_ws, out);
}